// Round 2
// baseline (907.817 us; speedup 1.0000x reference)
//
#include <hip/hip_runtime.h>
#include <hip/hip_cooperative_groups.h>
#include <math.h>

namespace cg = cooperative_groups;

#define BB 8
#define MM 2048
#define NNP 2048
#define THR2 0.25f
#define NITER 10
#define NPART 17
#define BLKPB 64                // blocks per batch
#define GRID (BB * BLKPB)       // 512 blocks, guaranteed co-resident at 2 blocks/CU
#define WPB 4                   // waves per block
#define MPW (MM / (BLKPB * WPB))// 8 source points per wave

// ---------------- pack: dest -> float4(x,y,z, valid? |d|^2 : INF), any_valid ----------------
__global__ void pack_kernel(const float* __restrict__ pc_dest,
                            float4* __restrict__ destp,
                            float* __restrict__ anyvalid)
{
    const int b = blockIdx.x;
    const int tid = threadIdx.x;
    __shared__ int anyf;
    if (tid == 0) anyf = 0;
    __syncthreads();
    int local = 0;
    for (int n = tid; n < NNP; n += blockDim.x) {
        float dx = pc_dest[(b * 3 + 0) * NNP + n];
        float dy = pc_dest[(b * 3 + 1) * NNP + n];
        float dz = pc_dest[(b * 3 + 2) * NNP + n];
        int valid = (dx != 0.0f) && (dy != 0.0f) && (dz != 0.0f);
        float dd = dx * dx + dy * dy + dz * dz;
        destp[b * NNP + n] = make_float4(dx, dy, dz, valid ? dd : INFINITY);
        local |= valid;
    }
    if (local) atomicOr(&anyf, 1);
    __syncthreads();
    if (tid == 0) anyvalid[b] = (anyf != 0) ? 1.0f : 0.0f;
}

// ---------------- Kabsch via Jacobi eigen of H^T H (double) ----------------
__device__ void kabsch3(const double H[3][3], double R[3][3])
{
    double A[3][3];
    for (int i = 0; i < 3; ++i)
        for (int j = 0; j < 3; ++j) {
            double s = 0.0;
            for (int k = 0; k < 3; ++k) s += H[k][i] * H[k][j];
            A[i][j] = s;
        }
    double V[3][3] = {{1,0,0},{0,1,0},{0,0,1}};
    const double nrm = A[0][0]*A[0][0] + A[1][1]*A[1][1] + A[2][2]*A[2][2] + 1e-300;
    for (int sweep = 0; sweep < 25; ++sweep) {
        const double off = A[0][1]*A[0][1] + A[0][2]*A[0][2] + A[1][2]*A[1][2];
        if (off < 1e-24 * nrm) break;
        for (int pi = 0; pi < 3; ++pi) {
            const int p = (pi == 2) ? 1 : 0;
            const int q = (pi == 0) ? 1 : 2;
            const double apq = A[p][q];
            if (fabs(apq) == 0.0) continue;
            const double theta = (A[q][q] - A[p][p]) / (2.0 * apq);
            const double t = ((theta >= 0.0) ? 1.0 : -1.0) / (fabs(theta) + sqrt(theta * theta + 1.0));
            const double c = 1.0 / sqrt(t * t + 1.0);
            const double s = t * c;
            const double app = A[p][p], aqq = A[q][q];
            A[p][p] = app - t * apq;
            A[q][q] = aqq + t * apq;
            A[p][q] = 0.0; A[q][p] = 0.0;
            const int r = 3 - p - q;
            const double arp = A[r][p], arq = A[r][q];
            A[r][p] = c * arp - s * arq; A[p][r] = A[r][p];
            A[r][q] = s * arp + c * arq; A[q][r] = A[r][q];
            for (int rr = 0; rr < 3; ++rr) {
                const double vrp = V[rr][p], vrq = V[rr][q];
                V[rr][p] = c * vrp - s * vrq;
                V[rr][q] = s * vrp + c * vrq;
            }
        }
    }
    double lam[3] = {A[0][0], A[1][1], A[2][2]};
    int ord[3] = {0, 1, 2};
    for (int i = 0; i < 2; ++i)
        for (int j = i + 1; j < 3; ++j)
            if (lam[ord[j]] > lam[ord[i]]) { const int tmp = ord[i]; ord[i] = ord[j]; ord[j] = tmp; }
    double Vs[3][3], U[3][3];
    for (int k = 0; k < 3; ++k) {
        const int c0 = ord[k];
        const double sk = sqrt(fmax(lam[c0], 0.0));
        const double inv = (sk > 1e-150) ? 1.0 / sk : 0.0;
        for (int i = 0; i < 3; ++i) {
            Vs[i][k] = V[i][c0];
            U[i][k] = (H[i][0] * V[0][c0] + H[i][1] * V[1][c0] + H[i][2] * V[2][c0]) * inv;
        }
    }
    const double detH = H[0][0] * (H[1][1] * H[2][2] - H[1][2] * H[2][1])
                      - H[0][1] * (H[1][0] * H[2][2] - H[1][2] * H[2][0])
                      + H[0][2] * (H[1][0] * H[2][1] - H[1][1] * H[2][0]);
    const double d = (detH < 0.0) ? -1.0 : 1.0;
    for (int i = 0; i < 3; ++i)
        for (int j = 0; j < 3; ++j)
            R[i][j] = Vs[i][0] * U[j][0] + Vs[i][1] * U[j][1] + d * Vs[i][2] * U[j][2];
}

// ---------------- fused ICP: all 10 iterations + final RMSE in one cooperative kernel ----------------
__global__ __launch_bounds__(256, 2) void icp_fused(
    const float* __restrict__ pc_src,
    const float4* __restrict__ destp,
    const float* __restrict__ anyvalid,
    const float* __restrict__ init_R,
    const float* __restrict__ init_t,
    float* __restrict__ blockpart,      // 2 * GRID * NPART (double-buffered by iteration parity)
    float* __restrict__ out)
{
    cg::grid_group grid = cg::this_grid();
    const int blk = blockIdx.x;
    const int b = blk / BLKPB;
    const int chunk = blk % BLKPB;
    const int tid = threadIdx.x;
    const int wid = tid >> 6;
    const int lane = tid & 63;

    __shared__ float Rt[12];            // R row-major (9) + t (3), per-block copy for batch b
    __shared__ float sm[WPB][NPART];
    __shared__ float sred[8][NPART];
    __shared__ double Sfin[NPART];

    if (tid < 9) Rt[tid] = init_R[b * 9 + tid];
    if (tid < 3) Rt[9 + tid] = init_t[b * 3 + tid];
    const float av = anyvalid[b];
    const float4* db = destp + b * NNP;
    const int wb = chunk * WPB + wid;   // wave index within batch, 0..255
    __syncthreads();

    for (int it = 0; it <= NITER; ++it) {
        // ---- corr phase: this wave's MPW source points ----
        const float R00 = Rt[0], R01 = Rt[1], R02 = Rt[2];
        const float R10 = Rt[3], R11 = Rt[4], R12 = Rt[5];
        const float R20 = Rt[6], R21 = Rt[7], R22 = Rt[8];
        const float t0 = Rt[9], t1 = Rt[10], t2 = Rt[11];

        float acc[NPART];
        #pragma unroll
        for (int k = 0; k < NPART; ++k) acc[k] = 0.0f;

        #pragma unroll 2
        for (int j = 0; j < MPW; ++j) {
            const int m = wb * MPW + j;
            const float sx = pc_src[0 * MM + m];
            const float sy = pc_src[1 * MM + m];
            const float sz = pc_src[2 * MM + m];
            const float px = R00 * sx + R01 * sy + R02 * sz + t0;
            const float py = R10 * sx + R11 * sy + R12 * sz + t1;
            const float pz = R20 * sx + R21 * sy + R22 * sz + t2;
            const float pp = px * px + py * py + pz * pz;

            float best = INFINITY;
            int bestn = 0;
            #pragma unroll 4
            for (int i = 0; i < NNP / 64; ++i) {
                const int n = i * 64 + lane;
                const float4 d = db[n];
                const float dot = px * d.x + py * d.y + pz * d.z;
                const float d2 = (pp + d.w) - 2.0f * dot;
                if (d2 < best) { best = d2; bestn = n; }
            }
            // cross-lane argmin, first-index tie-break (matches jnp.argmin)
            #pragma unroll
            for (int off = 32; off >= 1; off >>= 1) {
                const float ov = __shfl_xor(best, off);
                const int on = __shfl_xor(bestn, off);
                if (ov < best || (ov == best && on < bestn)) { best = ov; bestn = on; }
            }
            const float4 q = db[bestn];
            const float ex = px - q.x, ey = py - q.y, ez = pz - q.z;
            const float d2m = ex * ex + ey * ey + ez * ez;
            const float w = (d2m < THR2) ? av : 0.0f;

            // all lanes hold identical values -> accumulate (wave-uniform)
            acc[0] += w;
            acc[1] += w * sx;  acc[2] += w * sy;  acc[3] += w * sz;
            acc[4] += w * q.x; acc[5] += w * q.y; acc[6] += w * q.z;
            acc[7]  += w * sx * q.x; acc[8]  += w * sx * q.y; acc[9]  += w * sx * q.z;
            acc[10] += w * sy * q.x; acc[11] += w * sy * q.y; acc[12] += w * sy * q.z;
            acc[13] += w * sz * q.x; acc[14] += w * sz * q.y; acc[15] += w * sz * q.z;
            acc[16] += w * d2m;
        }

        if (lane == 0) {
            #pragma unroll
            for (int k = 0; k < NPART; ++k) sm[wid][k] = acc[k];
        }
        __syncthreads();
        float* bp_cur = blockpart + (size_t)(it & 1) * GRID * NPART;
        if (tid < NPART)
            bp_cur[blk * NPART + tid] = sm[0][tid] + sm[1][tid] + sm[2][tid] + sm[3][tid];

        grid.sync();

        // ---- every block redundantly reduces its batch's 64 rows ----
        {
            const int g = tid >> 5, kk = tid & 31;
            if (kk < NPART) {
                const float* bp = bp_cur + (size_t)(b * BLKPB + g * 8) * NPART + kk;
                float s = 0.0f;
                #pragma unroll
                for (int c = 0; c < 8; ++c) s += bp[c * NPART];
                sred[g][kk] = s;
            }
        }
        __syncthreads();
        if (tid < NPART) {
            double s = 0.0;
            #pragma unroll
            for (int g = 0; g < 8; ++g) s += (double)sred[g][tid];
            Sfin[tid] = s;
        }
        __syncthreads();

        if (it == NITER) break;

        // ---- thread 0: Kabsch update (redundant per block, deterministic) ----
        if (tid == 0) {
            const double wsum = Sfin[0];
            if (wsum >= 0.5) {
                const double safe = (wsum < 1.0) ? 1.0 : wsum;
                double mup[3], muq[3];
                for (int i = 0; i < 3; ++i) { mup[i] = Sfin[1 + i] / safe; muq[i] = Sfin[4 + i] / safe; }
                double H[3][3];
                for (int i = 0; i < 3; ++i)
                    for (int j = 0; j < 3; ++j)
                        H[i][j] = Sfin[7 + i * 3 + j] - Sfin[1 + i] * Sfin[4 + j] / safe;
                double R[3][3];
                kabsch3(H, R);
                for (int i = 0; i < 3; ++i) {
                    for (int j = 0; j < 3; ++j) Rt[i * 3 + j] = (float)R[i][j];
                    Rt[9 + i] = (float)(muq[i] - (R[i][0] * mup[0] + R[i][1] * mup[1] + R[i][2] * mup[2]));
                }
            }
        }
        __syncthreads();
    }

    // ---- output (one block per batch) ----
    if (chunk == 0) {
        if (tid == 0) {
            const double wsum = Sfin[0];
            const double wd2 = Sfin[16];
            const double safe = (wsum < 1.0) ? 1.0 : wsum;
            const float rmse = (float)sqrt(wd2 / safe);
            out[96 + b] = (wsum > 0.0) ? rmse : __builtin_nanf("");
        }
        if (tid < 9) out[b * 9 + tid] = Rt[tid];
        if (tid < 3) out[72 + b * 3 + tid] = Rt[9 + tid];
    }
}

extern "C" void kernel_launch(void* const* d_in, const int* in_sizes, int n_in,
                              void* d_out, int out_size, void* d_ws, size_t ws_size,
                              hipStream_t stream) {
    const float* pc_src  = (const float*)d_in[0];
    const float* pc_dest = (const float*)d_in[1];
    const float* init_R  = (const float*)d_in[2];
    const float* init_t  = (const float*)d_in[3];
    float* out = (float*)d_out;
    float* ws = (float*)d_ws;

    // ws layout (floats)
    float4* destp   = (float4*)ws;                      // BB*NNP*4
    float* anyvalid = ws + BB * NNP * 4;                // BB
    float* blockpart = anyvalid + BB;                   // 2*GRID*NPART

    pack_kernel<<<BB, 256, 0, stream>>>(pc_dest, destp, anyvalid);

    void* args[] = {(void*)&pc_src, (void*)&destp, (void*)&anyvalid,
                    (void*)&init_R, (void*)&init_t, (void*)&blockpart, (void*)&out};
    hipLaunchCooperativeKernel((const void*)icp_fused, dim3(GRID), dim3(256), args, 0, stream);
}

// Round 3
// 463.567 us; speedup vs baseline: 1.9583x; 1.9583x over previous
//
#include <hip/hip_runtime.h>
#include <hip/hip_cooperative_groups.h>
#include <math.h>

namespace cg = cooperative_groups;

#define BB 8
#define MM 2048
#define NNP 2048
#define THR2 0.25f
#define NITER 10
#define NPART 17
#define TPB 512
#define NWAVE 8                 // waves per block
#define GRIDB 256               // one block per CU
#define BPB (GRIDB / BB)        // 32 blocks per batch
#define SLICE (NNP / NWAVE)     // 256 dest points per wave

// ---------------- Kabsch via Jacobi eigen of H^T H (float, H pre-normalized ~O(1)) ----------------
__device__ void kabsch3f(const float H[3][3], float R[3][3])
{
    float A[3][3];
    for (int i = 0; i < 3; ++i)
        for (int j = 0; j < 3; ++j) {
            float s = 0.0f;
            for (int k = 0; k < 3; ++k) s += H[k][i] * H[k][j];
            A[i][j] = s;
        }
    float V[3][3] = {{1,0,0},{0,1,0},{0,0,1}};
    const float nrm = A[0][0]*A[0][0] + A[1][1]*A[1][1] + A[2][2]*A[2][2] + 1e-30f;
    for (int sweep = 0; sweep < 8; ++sweep) {
        const float off = A[0][1]*A[0][1] + A[0][2]*A[0][2] + A[1][2]*A[1][2];
        if (off < 1e-14f * nrm) break;
        for (int pi = 0; pi < 3; ++pi) {
            const int p = (pi == 2) ? 1 : 0;
            const int q = (pi == 0) ? 1 : 2;
            const float apq = A[p][q];
            if (apq == 0.0f) continue;
            const float theta = (A[q][q] - A[p][p]) / (2.0f * apq);
            const float t = ((theta >= 0.0f) ? 1.0f : -1.0f) / (fabsf(theta) + sqrtf(theta * theta + 1.0f));
            const float c = 1.0f / sqrtf(t * t + 1.0f);
            const float s = t * c;
            const float app = A[p][p], aqq = A[q][q];
            A[p][p] = app - t * apq;
            A[q][q] = aqq + t * apq;
            A[p][q] = 0.0f; A[q][p] = 0.0f;
            const int r = 3 - p - q;
            const float arp = A[r][p], arq = A[r][q];
            A[r][p] = c * arp - s * arq; A[p][r] = A[r][p];
            A[r][q] = s * arp + c * arq; A[q][r] = A[r][q];
            for (int rr = 0; rr < 3; ++rr) {
                const float vrp = V[rr][p], vrq = V[rr][q];
                V[rr][p] = c * vrp - s * vrq;
                V[rr][q] = s * vrp + c * vrq;
            }
        }
    }
    float lam[3] = {A[0][0], A[1][1], A[2][2]};
    int ord[3] = {0, 1, 2};
    for (int i = 0; i < 2; ++i)
        for (int j = i + 1; j < 3; ++j)
            if (lam[ord[j]] > lam[ord[i]]) { const int tmp = ord[i]; ord[i] = ord[j]; ord[j] = tmp; }
    float Vs[3][3], U[3][3];
    for (int k = 0; k < 3; ++k) {
        const int c0 = ord[k];
        const float sk = sqrtf(fmaxf(lam[c0], 0.0f));
        const float inv = (sk > 1e-12f) ? 1.0f / sk : 0.0f;
        for (int i = 0; i < 3; ++i) {
            Vs[i][k] = V[i][c0];
            U[i][k] = (H[i][0] * V[0][c0] + H[i][1] * V[1][c0] + H[i][2] * V[2][c0]) * inv;
        }
    }
    const float detH = H[0][0] * (H[1][1] * H[2][2] - H[1][2] * H[2][1])
                     - H[0][1] * (H[1][0] * H[2][2] - H[1][2] * H[2][0])
                     + H[0][2] * (H[1][0] * H[2][1] - H[1][1] * H[2][0]);
    const float d = (detH < 0.0f) ? -1.0f : 1.0f;
    for (int i = 0; i < 3; ++i)
        for (int j = 0; j < 3; ++j)
            R[i][j] = Vs[i][0] * U[j][0] + Vs[i][1] * U[j][1] + d * Vs[i][2] * U[j][2];
}

// ---------------- fused ICP: lane-owns-m, LDS-broadcast dest scan ----------------
__global__ __launch_bounds__(TPB) void icp_fused(
    const float* __restrict__ pc_src,
    const float* __restrict__ pc_dest,
    const float* __restrict__ init_R,
    const float* __restrict__ init_t,
    float* __restrict__ blockpart,      // 2 * GRIDB * NPART (parity double-buffered)
    float* __restrict__ out)
{
    cg::grid_group grid = cg::this_grid();
    const int blk = blockIdx.x;
    const int b = blk / BPB;
    const int cblk = blk % BPB;
    const int tid = threadIdx.x;
    const int wid = tid >> 6;
    const int lane = tid & 63;

    __shared__ float4 ds[NNP];          // 32 KB dest copy: (x,y,z, valid? |d|^2 : INF)
    __shared__ float sbest[NWAVE * 64];
    __shared__ int   sidx[NWAVE * 64];
    __shared__ float sred[BPB * NPART]; // 544
    __shared__ float Sfin[NPART];
    __shared__ float Rt[12];
    __shared__ int anyf;

    if (tid == 0) anyf = 0;
    if (tid < 9) Rt[tid] = init_R[b * 9 + tid];
    if (tid < 3) Rt[9 + tid] = init_t[b * 3 + tid];
    __syncthreads();

    // stage dest for this block's batch; fold validity into .w
    for (int n = tid; n < NNP; n += TPB) {
        const float dx = pc_dest[(b * 3 + 0) * NNP + n];
        const float dy = pc_dest[(b * 3 + 1) * NNP + n];
        const float dz = pc_dest[(b * 3 + 2) * NNP + n];
        const bool valid = (dx != 0.0f) && (dy != 0.0f) && (dz != 0.0f);
        const float dd = dx * dx + dy * dy + dz * dz;
        ds[n] = make_float4(dx, dy, dz, valid ? dd : INFINITY);
        const unsigned long long bal = __ballot(valid);
        if (lane == 0 && bal) atomicOr(&anyf, 1);
    }

    // this lane's source point (reference uses batch-0 source for all batches)
    const int m = cblk * 64 + lane;
    const float sx = pc_src[0 * MM + m];
    const float sy = pc_src[1 * MM + m];
    const float sz = pc_src[2 * MM + m];
    __syncthreads();
    const float av = anyf ? 1.0f : 0.0f;

    for (int it = 0; it <= NITER; ++it) {
        // ---- transform own point ----
        const float px = fmaf(Rt[0], sx, fmaf(Rt[1], sy, fmaf(Rt[2], sz, Rt[9])));
        const float py = fmaf(Rt[3], sx, fmaf(Rt[4], sy, fmaf(Rt[5], sz, Rt[10])));
        const float pz = fmaf(Rt[6], sx, fmaf(Rt[7], sy, fmaf(Rt[8], sz, Rt[11])));
        const float ppw = px * px + py * py + pz * pz;
        const float px2 = -2.0f * px, py2 = -2.0f * py, pz2 = -2.0f * pz;

        // ---- scan this wave's dest slice; 4 parallel best-chains for ILP ----
        const float4* dsp = ds + wid * SLICE;
        float b0 = INFINITY, b1 = INFINITY, b2 = INFINITY, b3 = INFINITY;
        int j0 = 0, j1 = 0, j2 = 0, j3 = 0;
        for (int i = 0; i < SLICE; i += 4) {
            const float4 d0 = dsp[i + 0];
            const float4 d1 = dsp[i + 1];
            const float4 d2 = dsp[i + 2];
            const float4 d3 = dsp[i + 3];
            const float e0 = fmaf(px2, d0.x, fmaf(py2, d0.y, fmaf(pz2, d0.z, ppw + d0.w)));
            const float e1 = fmaf(px2, d1.x, fmaf(py2, d1.y, fmaf(pz2, d1.z, ppw + d1.w)));
            const float e2 = fmaf(px2, d2.x, fmaf(py2, d2.y, fmaf(pz2, d2.z, ppw + d2.w)));
            const float e3 = fmaf(px2, d3.x, fmaf(py2, d3.y, fmaf(pz2, d3.z, ppw + d3.w)));
            if (e0 < b0) { b0 = e0; j0 = i; }
            if (e1 < b1) { b1 = e1; j1 = i; }
            if (e2 < b2) { b2 = e2; j2 = i; }
            if (e3 < b3) { b3 = e3; j3 = i; }
        }
        // merge chains, ties -> lower n (chain c holds n = j + c)
        float bv = b0; int bn = j0;
        if (b1 < bv || (b1 == bv && j1 + 1 < bn)) { bv = b1; bn = j1 + 1; }
        if (b2 < bv || (b2 == bv && j2 + 2 < bn)) { bv = b2; bn = j2 + 2; }
        if (b3 < bv || (b3 == bv && j3 + 3 < bn)) { bv = b3; bn = j3 + 3; }
        bn += wid * SLICE;
        sbest[wid * 64 + lane] = bv;
        sidx[wid * 64 + lane] = bn;
        __syncthreads();

        // ---- wave 0: combine slices (ascending wid => strict < keeps first index), moments ----
        if (wid == 0) {
            float best = sbest[lane];
            int bestn = sidx[lane];
            #pragma unroll
            for (int w = 1; w < NWAVE; ++w) {
                const float v = sbest[w * 64 + lane];
                if (v < best) { best = v; bestn = sidx[w * 64 + lane]; }
            }
            const float4 q = ds[bestn];
            const float ex = px - q.x, ey = py - q.y, ez = pz - q.z;
            const float d2m = ex * ex + ey * ey + ez * ez;
            const float w = (d2m < THR2) ? av : 0.0f;

            float mom[NPART];
            mom[0] = w;
            mom[1] = w * sx;  mom[2] = w * sy;  mom[3] = w * sz;
            mom[4] = w * q.x; mom[5] = w * q.y; mom[6] = w * q.z;
            mom[7]  = w * sx * q.x; mom[8]  = w * sx * q.y; mom[9]  = w * sx * q.z;
            mom[10] = w * sy * q.x; mom[11] = w * sy * q.y; mom[12] = w * sy * q.z;
            mom[13] = w * sz * q.x; mom[14] = w * sz * q.y; mom[15] = w * sz * q.z;
            mom[16] = w * d2m;
            #pragma unroll
            for (int k = 0; k < NPART; ++k) {
                float v = mom[k];
                v += __shfl_xor(v, 32);
                v += __shfl_xor(v, 16);
                v += __shfl_xor(v, 8);
                v += __shfl_xor(v, 4);
                v += __shfl_xor(v, 2);
                v += __shfl_xor(v, 1);
                mom[k] = v;
            }
            if (lane == 0) {
                float* bp = blockpart + (size_t)(it & 1) * GRIDB * NPART + (size_t)blk * NPART;
                #pragma unroll
                for (int k = 0; k < NPART; ++k) bp[k] = mom[k];
            }
        }

        grid.sync();

        // ---- every block reduces its batch's 32 rows (redundant, deterministic) ----
        const float* rows = blockpart + (size_t)(it & 1) * GRIDB * NPART + (size_t)b * BPB * NPART;
        for (int t = tid; t < BPB * NPART; t += TPB) sred[t] = rows[t];
        __syncthreads();
        if (tid < NPART) {
            float s = 0.0f;
            #pragma unroll
            for (int c = 0; c < BPB; ++c) s += sred[c * NPART + tid];
            Sfin[tid] = s;
        }
        __syncthreads();

        if (it == NITER) break;

        // ---- thread 0: Kabsch update ----
        if (tid == 0) {
            const float wsum = Sfin[0];
            if (wsum >= 0.5f) {
                const float safe = fmaxf(wsum, 1.0f);
                const float inv = 1.0f / safe;
                float mup[3], muq[3];
                for (int i = 0; i < 3; ++i) { mup[i] = Sfin[1 + i] * inv; muq[i] = Sfin[4 + i] * inv; }
                float H[3][3];
                for (int i = 0; i < 3; ++i)
                    for (int j = 0; j < 3; ++j)
                        H[i][j] = (Sfin[7 + i * 3 + j] * inv) - mup[i] * muq[j] * safe * inv;
                // note: (S7/safe - S1*S4/safe^2) = normalized H ~ O(1)
                float R[3][3];
                kabsch3f(H, R);
                for (int i = 0; i < 3; ++i) {
                    for (int j = 0; j < 3; ++j) Rt[i * 3 + j] = R[i][j];
                    Rt[9 + i] = muq[i] - (R[i][0] * mup[0] + R[i][1] * mup[1] + R[i][2] * mup[2]);
                }
            }
        }
        __syncthreads();
    }

    // ---- outputs: one block per batch ----
    if (cblk == 0) {
        if (tid == 0) {
            const float wsum = Sfin[0];
            const float safe = fmaxf(wsum, 1.0f);
            const float rmse = sqrtf(Sfin[16] / safe);
            out[96 + b] = (wsum > 0.0f) ? rmse : __builtin_nanf("");
        }
        if (tid < 9) out[b * 9 + tid] = Rt[tid];
        if (tid < 3) out[72 + b * 3 + tid] = Rt[9 + tid];
    }
}

extern "C" void kernel_launch(void* const* d_in, const int* in_sizes, int n_in,
                              void* d_out, int out_size, void* d_ws, size_t ws_size,
                              hipStream_t stream) {
    const float* pc_src  = (const float*)d_in[0];
    const float* pc_dest = (const float*)d_in[1];
    const float* init_R  = (const float*)d_in[2];
    const float* init_t  = (const float*)d_in[3];
    float* out = (float*)d_out;
    float* blockpart = (float*)d_ws;    // 2 * GRIDB * NPART floats

    void* args[] = {(void*)&pc_src, (void*)&pc_dest, (void*)&init_R,
                    (void*)&init_t, (void*)&blockpart, (void*)&out};
    hipLaunchCooperativeKernel((const void*)icp_fused, dim3(GRIDB), dim3(TPB), args, 0, stream);
}

// Round 4
// 448.755 us; speedup vs baseline: 2.0230x; 1.0330x over previous
//
#include <hip/hip_runtime.h>
#include <hip/hip_cooperative_groups.h>
#include <math.h>

namespace cg = cooperative_groups;

#define BB 8
#define MM 2048
#define NNP 2048
#define THR2 0.25f
#define NITER 10
#define NPART 17
#define TPB 1024
#define WPB 16                  // waves per block
#define GRIDB 256               // one block per CU
#define BPB (GRIDB / BB)        // 32 blocks per batch
#define TM 4                    // source points per wave (register-blocked)
#define MSPAN (WPB * TM)        // 64 m per block

// ---------------- Kabsch via Jacobi eigen of H^T H (float, H normalized ~O(1)) ----------------
__device__ void kabsch3f(const float H[3][3], float R[3][3])
{
    float A[3][3];
    for (int i = 0; i < 3; ++i)
        for (int j = 0; j < 3; ++j) {
            float s = 0.0f;
            for (int k = 0; k < 3; ++k) s += H[k][i] * H[k][j];
            A[i][j] = s;
        }
    float V[3][3] = {{1,0,0},{0,1,0},{0,0,1}};
    const float nrm = A[0][0]*A[0][0] + A[1][1]*A[1][1] + A[2][2]*A[2][2] + 1e-30f;
    for (int sweep = 0; sweep < 8; ++sweep) {
        const float off = A[0][1]*A[0][1] + A[0][2]*A[0][2] + A[1][2]*A[1][2];
        if (off < 1e-14f * nrm) break;
        for (int pi = 0; pi < 3; ++pi) {
            const int p = (pi == 2) ? 1 : 0;
            const int q = (pi == 0) ? 1 : 2;
            const float apq = A[p][q];
            if (apq == 0.0f) continue;
            const float theta = (A[q][q] - A[p][p]) / (2.0f * apq);
            const float t = ((theta >= 0.0f) ? 1.0f : -1.0f) / (fabsf(theta) + sqrtf(theta * theta + 1.0f));
            const float c = 1.0f / sqrtf(t * t + 1.0f);
            const float s = t * c;
            const float app = A[p][p], aqq = A[q][q];
            A[p][p] = app - t * apq;
            A[q][q] = aqq + t * apq;
            A[p][q] = 0.0f; A[q][p] = 0.0f;
            const int r = 3 - p - q;
            const float arp = A[r][p], arq = A[r][q];
            A[r][p] = c * arp - s * arq; A[p][r] = A[r][p];
            A[r][q] = s * arp + c * arq; A[q][r] = A[r][q];
            for (int rr = 0; rr < 3; ++rr) {
                const float vrp = V[rr][p], vrq = V[rr][q];
                V[rr][p] = c * vrp - s * vrq;
                V[rr][q] = s * vrp + c * vrq;
            }
        }
    }
    float lam[3] = {A[0][0], A[1][1], A[2][2]};
    int ord[3] = {0, 1, 2};
    for (int i = 0; i < 2; ++i)
        for (int j = i + 1; j < 3; ++j)
            if (lam[ord[j]] > lam[ord[i]]) { const int tmp = ord[i]; ord[i] = ord[j]; ord[j] = tmp; }
    float Vs[3][3], U[3][3];
    for (int k = 0; k < 3; ++k) {
        const int c0 = ord[k];
        const float sk = sqrtf(fmaxf(lam[c0], 0.0f));
        const float inv = (sk > 1e-12f) ? 1.0f / sk : 0.0f;
        for (int i = 0; i < 3; ++i) {
            Vs[i][k] = V[i][c0];
            U[i][k] = (H[i][0] * V[0][c0] + H[i][1] * V[1][c0] + H[i][2] * V[2][c0]) * inv;
        }
    }
    const float detH = H[0][0] * (H[1][1] * H[2][2] - H[1][2] * H[2][1])
                     - H[0][1] * (H[1][0] * H[2][2] - H[1][2] * H[2][0])
                     + H[0][2] * (H[1][0] * H[2][1] - H[1][1] * H[2][0]);
    const float d = (detH < 0.0f) ? -1.0f : 1.0f;
    for (int i = 0; i < 3; ++i)
        for (int j = 0; j < 3; ++j)
            R[i][j] = Vs[i][0] * U[j][0] + Vs[i][1] * U[j][1] + d * Vs[i][2] * U[j][2];
}

// ---------------- fused ICP: wave owns 4 uniform m's, lanes own dest sub-streams ----------------
__global__ __launch_bounds__(TPB, 4) void icp_fused(
    const float* __restrict__ pc_src,
    const float* __restrict__ pc_dest,
    const float* __restrict__ init_R,
    const float* __restrict__ init_t,
    float* __restrict__ blockpart,      // 2 * GRIDB * NPART (parity double-buffered)
    float* __restrict__ out)
{
    cg::grid_group grid = cg::this_grid();
    const int blk = blockIdx.x;
    const int b = blk / BPB;
    const int cblk = blk % BPB;
    const int tid = threadIdx.x;
    const int wid = tid >> 6;
    const int lane = tid & 63;

    __shared__ float4 ds[NNP];          // 32 KB dest copy: (x,y,z, valid? |d|^2 : INF)
    __shared__ float smom[WPB][NPART];
    __shared__ float sred[BPB * NPART]; // 544
    __shared__ float Sfin[NPART];
    __shared__ float Rt[12];
    __shared__ int anyf;

    if (tid == 0) anyf = 0;
    if (tid < 9) Rt[tid] = init_R[b * 9 + tid];
    if (tid < 3) Rt[9 + tid] = init_t[b * 3 + tid];
    __syncthreads();

    // stage dest for this block's batch once; fold validity into .w
    for (int n = tid; n < NNP; n += TPB) {
        const float dx = pc_dest[(b * 3 + 0) * NNP + n];
        const float dy = pc_dest[(b * 3 + 1) * NNP + n];
        const float dz = pc_dest[(b * 3 + 2) * NNP + n];
        const bool valid = (dx != 0.0f) && (dy != 0.0f) && (dz != 0.0f);
        const float dd = dx * dx + dy * dy + dz * dz;
        ds[n] = make_float4(dx, dy, dz, valid ? dd : INFINITY);
        const unsigned long long bal = __ballot(valid);
        if (lane == 0 && bal) atomicOr(&anyf, 1);
    }

    // this wave's 4 source points (wave-uniform; reference uses batch-0 source)
    const int m0 = cblk * MSPAN + wid * TM;
    float sx[TM], sy[TM], sz[TM];
    #pragma unroll
    for (int t = 0; t < TM; ++t) {
        sx[t] = pc_src[0 * MM + m0 + t];
        sy[t] = pc_src[1 * MM + m0 + t];
        sz[t] = pc_src[2 * MM + m0 + t];
    }
    __syncthreads();
    const float av = anyf ? 1.0f : 0.0f;

    for (int it = 0; it <= NITER; ++it) {
        // ---- transform the wave's m's (uniform) ----
        float px[TM], py[TM], pz[TM], pw[TM], nx[TM], ny[TM], nz[TM];
        #pragma unroll
        for (int t = 0; t < TM; ++t) {
            px[t] = fmaf(Rt[0], sx[t], fmaf(Rt[1], sy[t], fmaf(Rt[2], sz[t], Rt[9])));
            py[t] = fmaf(Rt[3], sx[t], fmaf(Rt[4], sy[t], fmaf(Rt[5], sz[t], Rt[10])));
            pz[t] = fmaf(Rt[6], sx[t], fmaf(Rt[7], sy[t], fmaf(Rt[8], sz[t], Rt[11])));
            pw[t] = px[t] * px[t] + py[t] * py[t] + pz[t] * pz[t];
            nx[t] = -2.0f * px[t]; ny[t] = -2.0f * py[t]; nz[t] = -2.0f * pz[t];
        }

        // ---- scan: lane streams dest[lane + 64*s]; 4 m-chains amortize each read ----
        float best[TM]; int bidx[TM];
        #pragma unroll
        for (int t = 0; t < TM; ++t) { best[t] = INFINITY; bidx[t] = lane; }

        #pragma unroll 4
        for (int s = 0; s < NNP / 64; ++s) {
            const int j = (s << 6) + lane;
            const float4 d = ds[j];
            #pragma unroll
            for (int t = 0; t < TM; ++t) {
                const float e = fmaf(nx[t], d.x, fmaf(ny[t], d.y, fmaf(nz[t], d.z, pw[t] + d.w)));
                if (e < best[t]) { best[t] = e; bidx[t] = j; }
            }
        }

        // ---- per-m cross-lane lex argmin (first-index tie-break), moments ----
        float acc[NPART];
        #pragma unroll
        for (int k = 0; k < NPART; ++k) acc[k] = 0.0f;

        #pragma unroll
        for (int t = 0; t < TM; ++t) {
            float bv = best[t]; int bn = bidx[t];
            #pragma unroll
            for (int off = 32; off >= 1; off >>= 1) {
                const float ov = __shfl_xor(bv, off);
                const int on = __shfl_xor(bn, off);
                if (ov < bv || (ov == bv && on < bn)) { bv = ov; bn = on; }
            }
            const float4 q = ds[bn];     // wave-uniform broadcast
            const float ex = px[t] - q.x, ey = py[t] - q.y, ez = pz[t] - q.z;
            const float d2m = ex * ex + ey * ey + ez * ez;
            const float w = (d2m < THR2) ? av : 0.0f;
            acc[0] += w;
            acc[1] += w * sx[t];  acc[2] += w * sy[t];  acc[3] += w * sz[t];
            acc[4] += w * q.x;    acc[5] += w * q.y;    acc[6] += w * q.z;
            acc[7]  += w * sx[t] * q.x; acc[8]  += w * sx[t] * q.y; acc[9]  += w * sx[t] * q.z;
            acc[10] += w * sy[t] * q.x; acc[11] += w * sy[t] * q.y; acc[12] += w * sy[t] * q.z;
            acc[13] += w * sz[t] * q.x; acc[14] += w * sz[t] * q.y; acc[15] += w * sz[t] * q.z;
            acc[16] += w * d2m;
        }
        if (lane == 0) {
            #pragma unroll
            for (int k = 0; k < NPART; ++k) smom[wid][k] = acc[k];
        }
        __syncthreads();
        if (tid < NPART) {
            float s = 0.0f;
            #pragma unroll
            for (int w = 0; w < WPB; ++w) s += smom[w][tid];
            blockpart[(size_t)(it & 1) * GRIDB * NPART + (size_t)blk * NPART + tid] = s;
        }

        grid.sync();

        // ---- every block reduces its batch's 32 rows (redundant, deterministic) ----
        const float* rows = blockpart + (size_t)(it & 1) * GRIDB * NPART + (size_t)b * BPB * NPART;
        if (tid < BPB * NPART) sred[tid] = rows[tid];
        __syncthreads();
        if (tid < NPART) {
            float s = 0.0f;
            #pragma unroll
            for (int c = 0; c < BPB; ++c) s += sred[c * NPART + tid];
            Sfin[tid] = s;
        }
        __syncthreads();

        if (it == NITER) break;

        // ---- thread 0: Kabsch update (redundant per block, deterministic) ----
        if (tid == 0) {
            const float wsum = Sfin[0];
            if (wsum >= 0.5f) {
                const float safe = fmaxf(wsum, 1.0f);
                const float inv = 1.0f / safe;
                float mup[3], muq[3];
                for (int i = 0; i < 3; ++i) { mup[i] = Sfin[1 + i] * inv; muq[i] = Sfin[4 + i] * inv; }
                float H[3][3];
                for (int i = 0; i < 3; ++i)
                    for (int j = 0; j < 3; ++j)
                        H[i][j] = (Sfin[7 + i * 3 + j] * inv) - mup[i] * muq[j];
                float R[3][3];
                kabsch3f(H, R);
                for (int i = 0; i < 3; ++i) {
                    for (int j = 0; j < 3; ++j) Rt[i * 3 + j] = R[i][j];
                    Rt[9 + i] = muq[i] - (R[i][0] * mup[0] + R[i][1] * mup[1] + R[i][2] * mup[2]);
                }
            }
        }
        __syncthreads();
    }

    // ---- outputs: one block per batch ----
    if (cblk == 0) {
        if (tid == 0) {
            const float wsum = Sfin[0];
            const float safe = fmaxf(wsum, 1.0f);
            const float rmse = sqrtf(Sfin[16] / safe);
            out[96 + b] = (wsum > 0.0f) ? rmse : __builtin_nanf("");
        }
        if (tid < 9) out[b * 9 + tid] = Rt[tid];
        if (tid < 3) out[72 + b * 3 + tid] = Rt[9 + tid];
    }
}

extern "C" void kernel_launch(void* const* d_in, const int* in_sizes, int n_in,
                              void* d_out, int out_size, void* d_ws, size_t ws_size,
                              hipStream_t stream) {
    const float* pc_src  = (const float*)d_in[0];
    const float* pc_dest = (const float*)d_in[1];
    const float* init_R  = (const float*)d_in[2];
    const float* init_t  = (const float*)d_in[3];
    float* out = (float*)d_out;
    float* blockpart = (float*)d_ws;    // 2 * GRIDB * NPART floats

    void* args[] = {(void*)&pc_src, (void*)&pc_dest, (void*)&init_R,
                    (void*)&init_t, (void*)&blockpart, (void*)&out};
    hipLaunchCooperativeKernel((const void*)icp_fused, dim3(GRIDB), dim3(TPB), args, 0, stream);
}

// Round 5
// 311.864 us; speedup vs baseline: 2.9109x; 1.4389x over previous
//
#include <hip/hip_runtime.h>
#include <math.h>

#define BB 8
#define MM 2048
#define NNP 2048
#define THR2 0.25f
#define NITER 10
#define SLOTS (NITER + 1)
#define NPART 17
#define TPB 1024
#define WPB 16                  // waves per block
#define GRIDB 256               // one block per CU
#define BPB (GRIDB / BB)        // 32 blocks per batch
#define TM 4                    // source points per wave (register-blocked)
#define MSPAN (WPB * TM)        // 64 m per block

// ---- ws layout (element counts) ----
#define ACC_N (SLOTS * BB * 32)     // float accum[SLOTS][BB][32] (17 used, padded)
#define RT_N  (SLOTS * BB * 16)     // float rtpub[SLOTS][BB][16] (12 used)
#define CN_N  (SLOTS * BB)          // uint arrive / flag

__device__ inline float ld_relax_f(const float* p) {
    return __hip_atomic_load(p, __ATOMIC_RELAXED, __HIP_MEMORY_SCOPE_AGENT);
}
__device__ inline unsigned ld_acq_u(const unsigned* p) {
    return __hip_atomic_load(p, __ATOMIC_ACQUIRE, __HIP_MEMORY_SCOPE_AGENT);
}

// ---------------- zero the sync/accumulator region (runs every call: replay-safe) ----------------
__global__ void zero_kernel(float* __restrict__ accum, float* __restrict__ rtpub,
                            unsigned* __restrict__ arrive, unsigned* __restrict__ flag)
{
    const int tid = blockIdx.x * blockDim.x + threadIdx.x;
    if (tid < ACC_N) __hip_atomic_store(&accum[tid], 0.0f, __ATOMIC_RELAXED, __HIP_MEMORY_SCOPE_AGENT);
    if (tid < RT_N)  __hip_atomic_store(&rtpub[tid], 0.0f, __ATOMIC_RELAXED, __HIP_MEMORY_SCOPE_AGENT);
    if (tid < CN_N) {
        __hip_atomic_store(&arrive[tid], 0u, __ATOMIC_RELAXED, __HIP_MEMORY_SCOPE_AGENT);
        __hip_atomic_store(&flag[tid], 0u, __ATOMIC_RELAXED, __HIP_MEMORY_SCOPE_AGENT);
    }
}

// ---------------- Kabsch via Jacobi eigen of H^T H (float, H normalized ~O(1)) ----------------
__device__ void kabsch3f(const float H[3][3], float R[3][3])
{
    float A[3][3];
    for (int i = 0; i < 3; ++i)
        for (int j = 0; j < 3; ++j) {
            float s = 0.0f;
            for (int k = 0; k < 3; ++k) s += H[k][i] * H[k][j];
            A[i][j] = s;
        }
    float V[3][3] = {{1,0,0},{0,1,0},{0,0,1}};
    const float nrm = A[0][0]*A[0][0] + A[1][1]*A[1][1] + A[2][2]*A[2][2] + 1e-30f;
    for (int sweep = 0; sweep < 8; ++sweep) {
        const float off = A[0][1]*A[0][1] + A[0][2]*A[0][2] + A[1][2]*A[1][2];
        if (off < 1e-14f * nrm) break;
        for (int pi = 0; pi < 3; ++pi) {
            const int p = (pi == 2) ? 1 : 0;
            const int q = (pi == 0) ? 1 : 2;
            const float apq = A[p][q];
            if (apq == 0.0f) continue;
            const float theta = (A[q][q] - A[p][p]) / (2.0f * apq);
            const float t = ((theta >= 0.0f) ? 1.0f : -1.0f) / (fabsf(theta) + sqrtf(theta * theta + 1.0f));
            const float c = 1.0f / sqrtf(t * t + 1.0f);
            const float s = t * c;
            const float app = A[p][p], aqq = A[q][q];
            A[p][p] = app - t * apq;
            A[q][q] = aqq + t * apq;
            A[p][q] = 0.0f; A[q][p] = 0.0f;
            const int r = 3 - p - q;
            const float arp = A[r][p], arq = A[r][q];
            A[r][p] = c * arp - s * arq; A[p][r] = A[r][p];
            A[r][q] = s * arp + c * arq; A[q][r] = A[r][q];
            for (int rr = 0; rr < 3; ++rr) {
                const float vrp = V[rr][p], vrq = V[rr][q];
                V[rr][p] = c * vrp - s * vrq;
                V[rr][q] = s * vrp + c * vrq;
            }
        }
    }
    float lam[3] = {A[0][0], A[1][1], A[2][2]};
    int ord[3] = {0, 1, 2};
    for (int i = 0; i < 2; ++i)
        for (int j = i + 1; j < 3; ++j)
            if (lam[ord[j]] > lam[ord[i]]) { const int tmp = ord[i]; ord[i] = ord[j]; ord[j] = tmp; }
    float Vs[3][3], U[3][3];
    for (int k = 0; k < 3; ++k) {
        const int c0 = ord[k];
        const float sk = sqrtf(fmaxf(lam[c0], 0.0f));
        const float inv = (sk > 1e-12f) ? 1.0f / sk : 0.0f;
        for (int i = 0; i < 3; ++i) {
            Vs[i][k] = V[i][c0];
            U[i][k] = (H[i][0] * V[0][c0] + H[i][1] * V[1][c0] + H[i][2] * V[2][c0]) * inv;
        }
    }
    const float detH = H[0][0] * (H[1][1] * H[2][2] - H[1][2] * H[2][1])
                     - H[0][1] * (H[1][0] * H[2][2] - H[1][2] * H[2][0])
                     + H[0][2] * (H[1][0] * H[2][1] - H[1][1] * H[2][0]);
    const float d = (detH < 0.0f) ? -1.0f : 1.0f;
    for (int i = 0; i < 3; ++i)
        for (int j = 0; j < 3; ++j)
            R[i][j] = Vs[i][0] * U[j][0] + Vs[i][1] * U[j][1] + d * Vs[i][2] * U[j][2];
}

// ---------------- fused ICP: per-batch producer/consumer sync, no grid.sync ----------------
__global__ __launch_bounds__(TPB, 4) void icp_fused(
    const float* __restrict__ pc_src,
    const float* __restrict__ pc_dest,
    const float* __restrict__ init_R,
    const float* __restrict__ init_t,
    float* __restrict__ accum,          // [SLOTS][BB][32]
    float* __restrict__ rtpub,          // [SLOTS][BB][16]
    unsigned* __restrict__ arrive,      // [SLOTS][BB]
    unsigned* __restrict__ flag,        // [SLOTS][BB]
    float* __restrict__ out)
{
    const int blk = blockIdx.x;
    const int b = blk / BPB;
    const int cblk = blk % BPB;
    const int tid = threadIdx.x;
    const int wid = tid >> 6;
    const int lane = tid & 63;

    __shared__ float4 ds[NNP];          // 32 KB dest copy: (x,y,z, valid? |d|^2 : INF)
    __shared__ float smom[WPB][NPART];
    __shared__ float Rt[12];
    __shared__ int anyf;

    if (tid == 0) anyf = 0;
    if (tid < 9) Rt[tid] = init_R[b * 9 + tid];
    if (tid < 3) Rt[9 + tid] = init_t[b * 3 + tid];
    __syncthreads();

    // stage dest for this block's batch once; fold validity into .w
    for (int n = tid; n < NNP; n += TPB) {
        const float dx = pc_dest[(b * 3 + 0) * NNP + n];
        const float dy = pc_dest[(b * 3 + 1) * NNP + n];
        const float dz = pc_dest[(b * 3 + 2) * NNP + n];
        const bool valid = (dx != 0.0f) && (dy != 0.0f) && (dz != 0.0f);
        const float dd = dx * dx + dy * dy + dz * dz;
        ds[n] = make_float4(dx, dy, dz, valid ? dd : INFINITY);
        const unsigned long long bal = __ballot(valid);
        if (lane == 0 && bal) atomicOr(&anyf, 1);
    }

    // this wave's 4 source points (wave-uniform; reference uses batch-0 source)
    const int m0 = cblk * MSPAN + wid * TM;
    float sx[TM], sy[TM], sz[TM];
    #pragma unroll
    for (int t = 0; t < TM; ++t) {
        sx[t] = pc_src[0 * MM + m0 + t];
        sy[t] = pc_src[1 * MM + m0 + t];
        sz[t] = pc_src[2 * MM + m0 + t];
    }
    __syncthreads();
    const float av = anyf ? 1.0f : 0.0f;

    for (int it = 0; it <= NITER; ++it) {
        // ---- transform the wave's m's (uniform) ----
        float px[TM], py[TM], pz[TM], pw[TM], nx[TM], ny[TM], nz[TM];
        #pragma unroll
        for (int t = 0; t < TM; ++t) {
            px[t] = fmaf(Rt[0], sx[t], fmaf(Rt[1], sy[t], fmaf(Rt[2], sz[t], Rt[9])));
            py[t] = fmaf(Rt[3], sx[t], fmaf(Rt[4], sy[t], fmaf(Rt[5], sz[t], Rt[10])));
            pz[t] = fmaf(Rt[6], sx[t], fmaf(Rt[7], sy[t], fmaf(Rt[8], sz[t], Rt[11])));
            pw[t] = px[t] * px[t] + py[t] * py[t] + pz[t] * pz[t];
            nx[t] = -2.0f * px[t]; ny[t] = -2.0f * py[t]; nz[t] = -2.0f * pz[t];
        }

        // ---- scan: lane streams dest[lane + 64*s]; 4 m-chains amortize each read ----
        float best[TM]; int bidx[TM];
        #pragma unroll
        for (int t = 0; t < TM; ++t) { best[t] = INFINITY; bidx[t] = lane; }

        #pragma unroll 4
        for (int s = 0; s < NNP / 64; ++s) {
            const int j = (s << 6) + lane;
            const float4 d = ds[j];
            #pragma unroll
            for (int t = 0; t < TM; ++t) {
                const float e = fmaf(nx[t], d.x, fmaf(ny[t], d.y, fmaf(nz[t], d.z, pw[t] + d.w)));
                if (e < best[t]) { best[t] = e; bidx[t] = j; }
            }
        }

        // ---- per-m cross-lane lex argmin (first-index tie-break), moments ----
        float acc[NPART];
        #pragma unroll
        for (int k = 0; k < NPART; ++k) acc[k] = 0.0f;

        #pragma unroll
        for (int t = 0; t < TM; ++t) {
            float bv = best[t]; int bn = bidx[t];
            #pragma unroll
            for (int off = 32; off >= 1; off >>= 1) {
                const float ov = __shfl_xor(bv, off);
                const int on = __shfl_xor(bn, off);
                if (ov < bv || (ov == bv && on < bn)) { bv = ov; bn = on; }
            }
            const float4 q = ds[bn];     // wave-uniform broadcast
            const float ex = px[t] - q.x, ey = py[t] - q.y, ez = pz[t] - q.z;
            const float d2m = ex * ex + ey * ey + ez * ez;
            const float w = (d2m < THR2) ? av : 0.0f;
            acc[0] += w;
            acc[1] += w * sx[t];  acc[2] += w * sy[t];  acc[3] += w * sz[t];
            acc[4] += w * q.x;    acc[5] += w * q.y;    acc[6] += w * q.z;
            acc[7]  += w * sx[t] * q.x; acc[8]  += w * sx[t] * q.y; acc[9]  += w * sx[t] * q.z;
            acc[10] += w * sy[t] * q.x; acc[11] += w * sy[t] * q.y; acc[12] += w * sy[t] * q.z;
            acc[13] += w * sz[t] * q.x; acc[14] += w * sz[t] * q.y; acc[15] += w * sz[t] * q.z;
            acc[16] += w * d2m;
        }
        if (lane == 0) {
            #pragma unroll
            for (int k = 0; k < NPART; ++k) smom[wid][k] = acc[k];
        }
        __syncthreads();

        // ---- block moments -> device accumulator (17 parallel atomic streams) ----
        if (tid < NPART) {
            float s = 0.0f;
            #pragma unroll
            for (int w = 0; w < WPB; ++w) s += smom[w][tid];
            __hip_atomic_fetch_add(&accum[(it * BB + b) * 32 + tid], s,
                                   __ATOMIC_RELAXED, __HIP_MEMORY_SCOPE_AGENT);
        }
        __syncthreads();    // ensure all 17 adds issued+complete before arrive
        if (tid == 0)
            __hip_atomic_fetch_add(&arrive[it * BB + b], 1u,
                                   __ATOMIC_RELEASE, __HIP_MEMORY_SCOPE_AGENT);

        if (it == NITER) break;

        // ---- batch leader: wait 32 arrivals, Kabsch, publish ----
        if (cblk == 0) {
            if (tid == 0) {
                while (ld_acq_u(&arrive[it * BB + b]) < (unsigned)BPB)
                    __builtin_amdgcn_s_sleep(2);
                float S[NPART];
                #pragma unroll
                for (int k = 0; k < NPART; ++k) S[k] = ld_relax_f(&accum[(it * BB + b) * 32 + k]);

                float newRt[12];
                #pragma unroll
                for (int k = 0; k < 12; ++k) newRt[k] = Rt[k];
                const float wsum = S[0];
                if (wsum >= 0.5f) {
                    const float safe = fmaxf(wsum, 1.0f);
                    const float inv = 1.0f / safe;
                    float mup[3], muq[3];
                    for (int i = 0; i < 3; ++i) { mup[i] = S[1 + i] * inv; muq[i] = S[4 + i] * inv; }
                    float H[3][3];
                    for (int i = 0; i < 3; ++i)
                        for (int j = 0; j < 3; ++j)
                            H[i][j] = (S[7 + i * 3 + j] * inv) - mup[i] * muq[j];
                    float R[3][3];
                    kabsch3f(H, R);
                    for (int i = 0; i < 3; ++i) {
                        for (int j = 0; j < 3; ++j) newRt[i * 3 + j] = R[i][j];
                        newRt[9 + i] = muq[i] - (R[i][0] * mup[0] + R[i][1] * mup[1] + R[i][2] * mup[2]);
                    }
                }
                #pragma unroll
                for (int k = 0; k < 12; ++k) {
                    __hip_atomic_store(&rtpub[(it * BB + b) * 16 + k], newRt[k],
                                       __ATOMIC_RELAXED, __HIP_MEMORY_SCOPE_AGENT);
                    Rt[k] = newRt[k];
                }
                __hip_atomic_store(&flag[it * BB + b], 1u,
                                   __ATOMIC_RELEASE, __HIP_MEMORY_SCOPE_AGENT);
            }
            __syncthreads();
        } else {
            // ---- followers: wait for published R/t ----
            if (tid == 0) {
                while (ld_acq_u(&flag[it * BB + b]) == 0u)
                    __builtin_amdgcn_s_sleep(2);
                #pragma unroll
                for (int k = 0; k < 12; ++k)
                    Rt[k] = ld_relax_f(&rtpub[(it * BB + b) * 16 + k]);
            }
            __syncthreads();
        }
    }

    // ---- outputs: batch leader only ----
    if (cblk == 0) {
        if (tid == 0) {
            while (ld_acq_u(&arrive[NITER * BB + b]) < (unsigned)BPB)
                __builtin_amdgcn_s_sleep(2);
            const float wsum = ld_relax_f(&accum[(NITER * BB + b) * 32 + 0]);
            const float wd2  = ld_relax_f(&accum[(NITER * BB + b) * 32 + 16]);
            const float safe = fmaxf(wsum, 1.0f);
            const float rmse = sqrtf(wd2 / safe);
            out[96 + b] = (wsum > 0.0f) ? rmse : __builtin_nanf("");
        }
        if (tid < 9) out[b * 9 + tid] = Rt[tid];
        if (tid < 3) out[72 + b * 3 + tid] = Rt[9 + tid];
    }
}

extern "C" void kernel_launch(void* const* d_in, const int* in_sizes, int n_in,
                              void* d_out, int out_size, void* d_ws, size_t ws_size,
                              hipStream_t stream) {
    const float* pc_src  = (const float*)d_in[0];
    const float* pc_dest = (const float*)d_in[1];
    const float* init_R  = (const float*)d_in[2];
    const float* init_t  = (const float*)d_in[3];
    float* out = (float*)d_out;

    float* accum     = (float*)d_ws;                 // ACC_N
    float* rtpub     = accum + ACC_N;                // RT_N
    unsigned* arrive = (unsigned*)(rtpub + RT_N);    // CN_N
    unsigned* flagp  = arrive + CN_N;                // CN_N

    zero_kernel<<<(ACC_N + 1023) / 1024, 1024, 0, stream>>>(accum, rtpub, arrive, flagp);

    void* args[] = {(void*)&pc_src, (void*)&pc_dest, (void*)&init_R, (void*)&init_t,
                    (void*)&accum, (void*)&rtpub, (void*)&arrive, (void*)&flagp, (void*)&out};
    hipLaunchCooperativeKernel((const void*)icp_fused, dim3(GRIDB), dim3(TPB), args, 0, stream);
}